// Round 3
// baseline (292.978 us; speedup 1.0000x reference)
//
#include <hip/hip_runtime.h>
#include <hip/hip_bf16.h>

// B=8, T=1024, D=512, H=8, DH=64, VS=512
typedef __bf16 bf16;
typedef __bf16 bf16x8 __attribute__((ext_vector_type(8)));
typedef float f32x4 __attribute__((ext_vector_type(4)));

#define NEGBIG (-3.0e38f)

__device__ inline f32x4 mfma16(bf16x8 a, bf16x8 b, f32x4 c) {
    return __builtin_amdgcn_mfma_f32_16x16x32_bf16(a, b, c, 0, 0, 0);
}
__device__ inline bf16x8 ld8(const bf16* p) { return *reinterpret_cast<const bf16x8*>(p); }
__device__ inline f32x4 ldf4(const float* p) { return *reinterpret_cast<const f32x4*>(p); }

// ---------------- pe table: [2048][64] bf16 ----------------
__global__ void pe_kernel(bf16* __restrict__ pe_b) {
    int l = blockIdx.x;          // 0..2047
    int d = threadIdx.x;         // 0..63
    float pos = (float)(l - 1024);
    int k = d & 31;
    float dv = expf(-(float)k * 0.29710775393471563f);   // ln(10000)/31
    float ang = pos * dv;
    float v = (d < 32) ? sinf(ang) : cosf(ang);
    pe_b[l * 64 + d] = (bf16)v;
}

// ---------------- vb table: [8][2048] fp32 ----------------
__global__ void vb_kernel(const float* __restrict__ v_bias, float* __restrict__ vb) {
    int t = blockIdx.x * 256 + threadIdx.x;   // h*2048 + l
    int h = t >> 11, l = t & 2047;
    float pos = (float)(l - 1024);
    float s = 0.f;
    #pragma unroll 4
    for (int d = 0; d < 32; d++) {
        float dv = expf(-(float)d * 0.29710775393471563f);
        float ang = pos * dv;
        s += v_bias[h * 64 + d] * sinf(ang) + v_bias[h * 64 + 32 + d] * cosf(ang);
    }
    vb[t] = s;
}

// ---------------- 8192x512x512 GEMM + bias, bf16 MFMA, fp32 accum ----------------
// MODE 0: A fp32, out bf16 at [((b*8+h)*1024+t)*64+dh]   (q_ws / v_ws)
// MODE 1: A bf16, out fp32 at [row*512+col]              (d_out)
template<int MODE>
__global__ __launch_bounds__(256) void proj_gemm(const void* __restrict__ Ap, const float* __restrict__ W,
                                                 const float* __restrict__ bias, void* __restrict__ outp) {
    __shared__ bf16 As[64][40];   // [m][k]
    __shared__ bf16 Wt[64][40];   // [n][k]
    int row0 = blockIdx.x * 64, n0 = blockIdx.y * 64;
    int tid = threadIdx.x, lane = tid & 63, w = tid >> 6, lg = lane >> 4, lr = lane & 15;
    int wm = (w >> 1) * 32, wn = (w & 1) * 32;
    f32x4 acc[2][2] = {};
    for (int k0 = 0; k0 < 512; k0 += 32) {
        int r = tid >> 2, kq = (tid & 3) * 8;
        bf16x8 av;
        if (MODE == 0) {
            const float* A = (const float*)Ap;
            f32x4 a0 = ldf4(A + (row0 + r) * 512 + k0 + kq);
            f32x4 a1 = ldf4(A + (row0 + r) * 512 + k0 + kq + 4);
            #pragma unroll
            for (int e = 0; e < 4; e++) { av[e] = (bf16)a0[e]; av[4 + e] = (bf16)a1[e]; }
        } else {
            av = ld8((const bf16*)Ap + (row0 + r) * 512 + k0 + kq);
        }
        int kk = tid >> 3, n8 = (tid & 7) * 8;
        f32x4 w0 = ldf4(W + (k0 + kk) * 512 + n0 + n8);
        f32x4 w1 = ldf4(W + (k0 + kk) * 512 + n0 + n8 + 4);
        __syncthreads();
        *reinterpret_cast<bf16x8*>(&As[r][kq]) = av;
        #pragma unroll
        for (int e = 0; e < 4; e++) { Wt[n8 + e][kk] = (bf16)w0[e]; Wt[n8 + 4 + e][kk] = (bf16)w1[e]; }
        __syncthreads();
        bf16x8 a0 = ld8(&As[wm + lr][lg * 8]);
        bf16x8 a1 = ld8(&As[wm + 16 + lr][lg * 8]);
        bf16x8 b0 = ld8(&Wt[wn + lr][lg * 8]);
        bf16x8 b1 = ld8(&Wt[wn + 16 + lr][lg * 8]);
        acc[0][0] = mfma16(a0, b0, acc[0][0]);
        acc[0][1] = mfma16(a0, b1, acc[0][1]);
        acc[1][0] = mfma16(a1, b0, acc[1][0]);
        acc[1][1] = mfma16(a1, b1, acc[1][1]);
    }
    #pragma unroll
    for (int mi = 0; mi < 2; mi++)
    #pragma unroll
    for (int ni = 0; ni < 2; ni++)
    #pragma unroll
    for (int rr = 0; rr < 4; rr++) {
        int row = row0 + wm + mi * 16 + lg * 4 + rr;
        int col = n0 + wn + ni * 16 + lr;
        float v = (float)acc[mi][ni][rr] + bias[col];
        if (MODE == 0) {
            int b = row >> 10, t = row & 1023, h = col >> 6, dh = col & 63;
            ((bf16*)outp)[(((b * 8 + h) << 10) + t) * 64 + dh] = (bf16)v;
        } else {
            ((float*)outp)[row * 512 + col] = v;
        }
    }
}

// ---------------- fused TENER attention ----------------
// grid: (64 bh, 16 q-tiles), block 256 (4 waves x 16 rows each)
__global__ __launch_bounds__(256) void tener_attn(const bf16* __restrict__ qw, const float* __restrict__ kin,
                                                  const bf16* __restrict__ vw, const int* __restrict__ mask,
                                                  const bf16* __restrict__ peb, const float* __restrict__ vb,
                                                  bf16* __restrict__ xw) {
    __shared__ bf16 Vt[64][72];        // [dh][j] transposed V tile
    __shared__ bf16 Ks[64][72];        // [j][dh] K tile (bf16, converted)
    __shared__ float Rl[4][16][80];    // per-wave rel band R[row][u]
    __shared__ bf16 Pl[4][16][72];     // per-wave P tile [row][jj]
    int bh = blockIdx.x, i0 = blockIdx.y * 64;
    int b = bh >> 3, h = bh & 7;
    int tid = threadIdx.x, w = tid >> 6, lane = tid & 63, lg = lane >> 4, lr = lane & 15;
    int rbase = i0 + w * 16;

    bf16x8 aq[2];
    aq[0] = ld8(qw + ((bh << 10) + rbase + lr) * 64 + lg * 8);
    aq[1] = ld8(qw + ((bh << 10) + rbase + lr) * 64 + 32 + lg * 8);

    f32x4 o[4] = {};
    float m_[4], d_[4];
    #pragma unroll
    for (int r = 0; r < 4; r++) { m_[r] = NEGBIG; d_[r] = 0.f; }

    for (int j0 = 0; j0 < 1024; j0 += 64) {
        // global loads for staging (issue before barrier)
        int vj = tid >> 2, dq = (tid & 3) * 16;
        const bf16* vsrc = vw + ((bh << 10) + j0 + vj) * 64 + dq;
        bf16x8 v0 = ld8(vsrc), v1 = ld8(vsrc + 8);
        const float* ksrc = kin + ((b << 10) + j0 + vj) * 512 + (h << 6) + dq;
        f32x4 kf0 = ldf4(ksrc), kf1 = ldf4(ksrc + 4), kf2 = ldf4(ksrc + 8), kf3 = ldf4(ksrc + 12);

        __syncthreads();   // A: prior iter's Vt/Ks/Pl reads done

        #pragma unroll
        for (int e = 0; e < 8; e++) { Vt[dq + e][vj] = v0[e]; Vt[dq + 8 + e][vj] = v1[e]; }
        bf16x8 kc0, kc1;
        #pragma unroll
        for (int e = 0; e < 4; e++) {
            kc0[e] = (bf16)kf0[e]; kc0[4 + e] = (bf16)kf1[e];
            kc1[e] = (bf16)kf2[e]; kc1[4 + e] = (bf16)kf3[e];
        }
        *reinterpret_cast<bf16x8*>(&Ks[vj][dq]) = kc0;
        *reinterpret_cast<bf16x8*>(&Ks[vj][dq + 8]) = kc1;

        // rel band: R[rl][u] = q_row . pe[L0-16+u], u in [0,80)  (reads global peb only)
        int L0 = 1024 + j0 - i0 - w * 16;
        #pragma unroll
        for (int ut = 0; ut < 5; ut++) {
            f32x4 acc = {};
            #pragma unroll
            for (int ks = 0; ks < 2; ks++) {
                int l = L0 - 16 + ut * 16 + lr;
                bf16x8 bp = ld8(peb + l * 64 + ks * 32 + lg * 8);
                acc = mfma16(aq[ks], bp, acc);
            }
            #pragma unroll
            for (int r = 0; r < 4; r++) Rl[w][lg * 4 + r][ut * 16 + lr] = acc[r];
        }

        __syncthreads();   // B: Vt + Ks + Rl visible

        // S = q . k^T from Ks
        f32x4 s[4];
        #pragma unroll
        for (int nt = 0; nt < 4; nt++) {
            f32x4 acc = {};
            #pragma unroll
            for (int ks = 0; ks < 2; ks++) {
                bf16x8 bk = ld8(&Ks[nt * 16 + lr][ks * 32 + lg * 8]);
                acc = mfma16(aq[ks], bk, acc);
            }
            s[nt] = acc;
        }

        // logits + online softmax (rows = lg*4+r, cols = nt*16+lr)
        int mk[4];
        #pragma unroll
        for (int nt = 0; nt < 4; nt++) mk[nt] = mask[(b << 10) + j0 + nt * 16 + lr];
        #pragma unroll
        for (int r = 0; r < 4; r++) {
            int rl = lg * 4 + r;
            float sv[4];
            #pragma unroll
            for (int nt = 0; nt < 4; nt++) {
                int jj = nt * 16 + lr;
                float x = (float)s[nt][r] + Rl[w][rl][jj - rl + 16] + vb[(h << 11) + L0 + jj - rl];
                sv[nt] = mk[nt] ? x : NEGBIG;
            }
            float mx = fmaxf(fmaxf(sv[0], sv[1]), fmaxf(sv[2], sv[3]));
            #pragma unroll
            for (int off = 1; off < 16; off <<= 1) mx = fmaxf(mx, __shfl_xor(mx, off));
            float nm = fmaxf(m_[r], mx);
            float sc = expf(m_[r] - nm);
            float p[4], rs = 0.f;
            #pragma unroll
            for (int nt = 0; nt < 4; nt++) {
                p[nt] = mk[nt] ? expf(sv[nt] - nm) : 0.f;
                rs += p[nt];
            }
            #pragma unroll
            for (int off = 1; off < 16; off <<= 1) rs += __shfl_xor(rs, off);
            d_[r] = d_[r] * sc + rs;
            m_[r] = nm;
            #pragma unroll
            for (int dt = 0; dt < 4; dt++) o[dt][r] *= sc;
            #pragma unroll
            for (int nt = 0; nt < 4; nt++) Pl[w][rl][nt * 16 + lr] = (bf16)p[nt];
        }

        __syncthreads();   // C: Pl visible

        // O += P . V
        #pragma unroll
        for (int ks = 0; ks < 2; ks++) {
            bf16x8 ap = ld8(&Pl[w][lr][ks * 32 + lg * 8]);
            #pragma unroll
            for (int dt = 0; dt < 4; dt++) {
                bf16x8 bv = ld8(&Vt[dt * 16 + lr][ks * 32 + lg * 8]);
                o[dt] = mfma16(ap, bv, o[dt]);
            }
        }
    }

    // epilogue: x[b, i, h*64+dh] = O/d  (bf16)
    #pragma unroll
    for (int dt = 0; dt < 4; dt++)
    #pragma unroll
    for (int r = 0; r < 4; r++) {
        int row = rbase + lg * 4 + r;
        float denom = d_[r];
        float v = denom > 0.f ? (float)o[dt][r] / denom : 0.f;
        xw[(((b << 10) + row) << 9) + (h << 6) + dt * 16 + lr] = (bf16)v;
    }
}

extern "C" void kernel_launch(void* const* d_in, const int* in_sizes, int n_in,
                              void* d_out, int out_size, void* d_ws, size_t ws_size,
                              hipStream_t stream) {
    const float* query  = (const float*)d_in[0];
    const float* key_in = (const float*)d_in[1];
    const float* value  = (const float*)d_in[2];
    const int*   mask   = (const int*)d_in[3];
    const float* Wq     = (const float*)d_in[4];
    const float* bq     = (const float*)d_in[5];
    const float* Wv     = (const float*)d_in[6];
    const float* bv     = (const float*)d_in[7];
    const float* Wo     = (const float*)d_in[8];
    const float* bo     = (const float*)d_in[9];
    const float* v_bias = (const float*)d_in[10];

    char* ws = (char*)d_ws;
    bf16*  pe_b = (bf16*)(ws);                           // 256 KB
    float* vb   = (float*)(ws + 262144);                 // 64 KB
    bf16*  q_ws = (bf16*)(ws + 327680);                  // 8 MB  [bh][t][dh]
    bf16*  v_ws = (bf16*)(ws + 327680 + 8388608);        // 8 MB  [bh][t][dh]
    bf16*  x_ws = (bf16*)(ws + 327680 + 16777216);       // 8 MB  [b*t][512]

    pe_kernel<<<2048, 64, 0, stream>>>(pe_b);
    vb_kernel<<<64, 256, 0, stream>>>(v_bias, vb);
    proj_gemm<0><<<dim3(128, 8), 256, 0, stream>>>(query, Wq, bq, q_ws);
    proj_gemm<0><<<dim3(128, 8), 256, 0, stream>>>(value, Wv, bv, v_ws);
    tener_attn<<<dim3(64, 16), 256, 0, stream>>>(q_ws, key_in, v_ws, mask, pe_b, vb, x_ws);
    proj_gemm<1><<<dim3(128, 8), 256, 0, stream>>>(x_ws, Wo, bo, d_out);
}